// Round 14
// baseline (62.486 us; speedup 1.0000x reference)
//
#include <hip/hip_runtime.h>
#include <hip/hip_bf16.h>
#include <math.h>

// Problem constants
#define Q_N 100
#define G_N 50
#define P_N 24
#define RS_N 96
#define GRID_N 9216
#define THICK 0.03f
#define SHARP 80.0f
#define PTS_W 5.0f
#define TAN_W 1.0f
#define CURV_W 0.5f
#define OVL_W 2.0f

// Workspace layout (float offsets). fp16 regions: n_ushorts/2 floats.
// PM padded to 112 rows, GM to 64 rows for 16x16 MFMA tiles (pad reads garbage,
// never flows into valid (i<100,j<50) outputs).
#define PRS_OFF  0                  // pred_rs: 100*192 = 19200 floats
#define GRS_OFF  19200              // gt_rs:   50*192  = 9600  -> 28800
#define PMB_OFF  28800              // PM fp16: 112*9216 ushort = 516096 f -> 544896
#define GMB_OFF  544896             // GM fp16:  64*9216 ushort = 294912 f -> 839808
#define ROWP_OFF 839808             // pred row-sum partials: 100*9 -> 840708
#define ROWG_OFF 840708             // gt   row-sum partials:  50*9 -> 841158
#define INTP_OFF 841216             // inter partials: 9 x 112 x 64 = 64512 -> 905728

typedef float    f32x2 __attribute__((ext_vector_type(2)));
typedef float    f32x4 __attribute__((ext_vector_type(4)));
typedef _Float16 f16x8 __attribute__((ext_vector_type(8)));

__device__ __forceinline__ float smooth_l1(float x) {
    float a = fabsf(x);
    return (a < 1.0f) ? 0.5f * a * a : a - 0.5f;
}
__device__ __forceinline__ float fast_rcp(float x) {
#if __has_builtin(__builtin_amdgcn_rcpf)
    return __builtin_amdgcn_rcpf(x);
#else
    return 1.0f / x;
#endif
}
__device__ __forceinline__ float fast_sqrt(float x) {
#if __has_builtin(__builtin_amdgcn_sqrtf)
    return __builtin_amdgcn_sqrtf(x);
#else
    return sqrtf(x);
#endif
}
__device__ __forceinline__ float fast_rsq(float x) {
#if __has_builtin(__builtin_amdgcn_rsqf)
    return __builtin_amdgcn_rsqf(x);
#else
    return 1.0f / sqrtf(x);
#endif
}

// ---- Kernel 1: soft masks (fp16) + row-sum partials + fused resample ----
__global__ __launch_bounds__(256)
void mask_kernel(const float* __restrict__ pred,
                 const float* __restrict__ gt,
                 const float* __restrict__ vis,
                 float* __restrict__ ws) {
    int row   = blockIdx.x / 9;         // 0..149
    int chunk = blockIdx.x % 9;         // 1024 grid pts each
    int tid = threadIdx.x;              // 0..255
    bool isPred = row < Q_N;
    __shared__ float ptx[P_N], pty[P_N], pvv[P_N];
    __shared__ float4 seg[P_N-1];
    __shared__ float  sinv[P_N-1];
    __shared__ int s_noseg;
    __shared__ float wsum[4];
    __shared__ float cum[P_N];
    __shared__ float s_total;

    if (tid < P_N) {
        const float* src = isPred ? pred + row * (P_N*2) : gt + (row - Q_N) * (P_N*2);
        float2 p = ((const float2*)src)[tid];
        ptx[tid] = p.x; pty[tid] = p.y;
    }
    if (tid == 0) {
        s_noseg = 1;
        if (isPred) {
            for (int k = 0; k < P_N; k++) pvv[k] = 1.0f;
        } else {
            const float* v = vis + (row - Q_N) * P_N;
            int cnt = 0;
            for (int k = 0; k < P_N; k++) {
                int r = (v[k] > 0.5f) ? 1 : 0;
                cnt += r;
                pvv[k] = (float)r;
            }
            if (cnt < 2) for (int k = 0; k < P_N; k++) pvv[k] = 1.0f;
        }
    }
    __syncthreads();
    if (tid < P_N-1) {
        bool v = pvv[tid] * pvv[tid+1] > 0.5f;
        if (v) {
            float ax = ptx[tid], ay = pty[tid];
            float abx = ptx[tid+1]-ax, aby = pty[tid+1]-ay;
            seg[tid] = make_float4(ax, ay, abx, aby);
            sinv[tid] = fast_rcp(fmaxf(abx*abx + aby*aby, 1e-8f));
            s_noseg = 0;                 // benign race: all writers write 0
        } else {
            seg[tid] = make_float4(1e18f, 1e18f, 0.0f, 0.0f);
            sinv[tid] = 0.0f;
        }
    }
    __syncthreads();

    int g0 = chunk * 1024 + tid * 4;    // 4 consecutive grid pts, same grid row
    float y  = (float)(g0 >> 7) * (1.0f/71.0f);
    float x0 = (float)(g0 & 127) * (1.0f/127.0f);
    f32x2 xs01 = { x0,                  x0 + 1.0f/127.0f };
    f32x2 xs23 = { x0 + 2.0f/127.0f,    x0 + 3.0f/127.0f };
    f32x2 m01 = {3.0e38f, 3.0e38f}, m23 = {3.0e38f, 3.0e38f};
    #pragma unroll
    for (int k = 0; k < P_N-1; k++) {
        float4 sg = seg[k];
        float inv = sinv[k];
        float apy = y - sg.y;
        float dwy = apy * sg.w;
        f32x2 apx01 = xs01 - sg.x;
        f32x2 apx23 = xs23 - sg.x;
        f32x2 t01 = (apx01*sg.z + dwy) * inv;
        f32x2 t23 = (apx23*sg.z + dwy) * inv;
        t01.x = fminf(fmaxf(t01.x, 0.0f), 1.0f);
        t01.y = fminf(fmaxf(t01.y, 0.0f), 1.0f);
        t23.x = fminf(fmaxf(t23.x, 0.0f), 1.0f);
        t23.y = fminf(fmaxf(t23.y, 0.0f), 1.0f);
        f32x2 dx01 = apx01 - t01*sg.z;
        f32x2 dy01 = apy   - t01*sg.w;
        f32x2 dx23 = apx23 - t23*sg.z;
        f32x2 dy23 = apy   - t23*sg.w;
        f32x2 d01 = dx01*dx01 + dy01*dy01;
        f32x2 d23 = dx23*dx23 + dy23*dy23;
        m01.x = fminf(m01.x, d01.x); m01.y = fminf(m01.y, d01.y);
        m23.x = fminf(m23.x, d23.x); m23.y = fminf(m23.y, d23.y);
    }
    float m2[4] = { m01.x, m01.y, m23.x, m23.y };
    if (s_noseg) {
        float xs[4] = { xs01.x, xs01.y, xs23.x, xs23.y };
        #pragma unroll
        for (int u = 0; u < 4; u++) m2[u] = 3.0e38f;
        for (int k = 0; k < P_N; k++) {
            if (pvv[k] > 0.5f) {
                #pragma unroll
                for (int u = 0; u < 4; u++) {
                    float dx = xs[u] - ptx[k], dy = y - pty[k];
                    m2[u] = fminf(m2[u], dx*dx + dy*dy);
                }
            }
        }
    }
    ushort4 o;
    unsigned short* ov = &o.x;
    float lsum = 0.0f;
    #pragma unroll
    for (int u = 0; u < 4; u++) {
        float mind = fast_sqrt(fmaxf(m2[u], 1e-12f));
        float z = (THICK - mind) * SHARP;
        float s = fast_rcp(1.0f + __expf(-z));
        _Float16 h = (_Float16)s;                  // RNE f32->f16
        ov[u] = __builtin_bit_cast(unsigned short, h);
        lsum += (float)h;                          // sums consistent with quantized masks
    }
    unsigned short* base = (unsigned short*)(ws + (isPred ? PMB_OFF : GMB_OFF))
                         + (size_t)(isPred ? row : row - Q_N) * GRID_N;
    ((ushort4*)base)[g0 >> 2] = o;

    // deterministic block reduction of lsum
    #pragma unroll
    for (int off = 32; off > 0; off >>= 1) lsum += __shfl_down(lsum, off);
    if ((tid & 63) == 0) wsum[tid >> 6] = lsum;
    __syncthreads();
    if (tid == 0) {
        float s = (wsum[0] + wsum[1]) + (wsum[2] + wsum[3]);
        if (isPred) ws[ROWP_OFF + row*9 + chunk] = s;
        else        ws[ROWG_OFF + (row - Q_N)*9 + chunk] = s;
    }

    // ---- fused resample: only chunk-0 blocks ----
    if (chunk == 0) {
        if (tid == 0) {
            float c = 0.0f;
            cum[0] = 0.0f;
            for (int k = 0; k < P_N-1; k++) {
                float dx = ptx[k+1]-ptx[k], dy = pty[k+1]-pty[k];
                float len = sqrtf(fmaxf(dx*dx + dy*dy, 1e-12f));  // _safe_norm (keep IEEE)
                float valid = pvv[k]*pvv[k+1];
                c += len * valid;
                cum[k+1] = c;
            }
            s_total = c;
        }
        __syncthreads();
        float total = s_total;
        if (tid < RS_N) {
            float ox, oy;
            if (total < 1e-8f) {
                ox = ptx[0]; oy = pty[0];
            } else {
                float t = ((float)tid / 95.0f) * total;
                // searchsorted(cum, t, side='right') - 1 == count(cum <= t) - 1
                int idx = -1;
                for (int k = 0; k < P_N; k++) idx += (cum[k] <= t) ? 1 : 0;
                idx = min(max(idx, 0), P_N-2);
                float lt = cum[idx], rt = cum[idx+1];
                float alpha = (t - lt) / fmaxf(rt - lt, 1e-8f);
                ox = ptx[idx] + alpha * (ptx[idx+1]-ptx[idx]);
                oy = pty[idx] + alpha * (pty[idx+1]-pty[idx]);
            }
            float* dst = isPred ? ws + PRS_OFF + row * (RS_N*2)
                                : ws + GRS_OFF + (row - Q_N) * (RS_N*2);
            dst[2*tid]   = ox;
            dst[2*tid+1] = oy;
        }
    }
}

// ---- Kernel 2: inter = PM (fp16) x GM^T (fp16) via MFMA, K-split x9 ----
__global__ __launch_bounds__(64)
void inter_kernel(float* __restrict__ ws) {
    int bid = blockIdx.x;               // 7 x 4 x 9 = 252
    int mt = bid % 7;
    int nt = (bid / 7) & 3;
    int kc = bid / 28;                  // 0..8
    int l = threadIdx.x;
    const unsigned short* PMB = (const unsigned short*)(ws + PMB_OFF);
    const unsigned short* GMB = (const unsigned short*)(ws + GMB_OFF);
    int i0 = mt*16, j0 = nt*16, k0 = kc*1024;
    const f16x8* pa = (const f16x8*)(PMB + (size_t)(i0 + (l & 15)) * GRID_N + k0 + 8*(l >> 4));
    const f16x8* pb = (const f16x8*)(GMB + (size_t)(j0 + (l & 15)) * GRID_N + k0 + 8*(l >> 4));
    f32x4 acc = {0.0f, 0.0f, 0.0f, 0.0f};
    #pragma unroll 8
    for (int s = 0; s < 32; s++) {
        acc = __builtin_amdgcn_mfma_f32_16x16x32_f16(pa[s*4], pb[s*4], acc, 0, 0, 0);
    }
    // D: col = l&15, row = 4*(l>>4) + v
    float* dst = ws + INTP_OFF + kc * 7168;     // 112*64
    int r0 = 4*(l >> 4), c = l & 15;
    #pragma unroll
    for (int v = 0; v < 4; v++) {
        dst[(i0 + r0 + v) * 64 + (j0 + c)] = acc[v];
    }
}

// ---- Kernel 3: 2x2 pair tile per 256-thread block; fully unrolled chamfer ----
__global__ __launch_bounds__(256)
void pair_kernel(const float* __restrict__ ws, float* __restrict__ out) {
    int bi = blockIdx.x / 25;           // i0 = 2*bi
    int bj = blockIdx.x % 25;           // j0 = 2*bj
    int i0 = bi*2, j0 = bj*2;
    int tid = threadIdx.x;
    int w = tid >> 6;                   // wave 0..3
    int l = tid & 63;
    int wi = w >> 1, wj = w & 1;
    int i = i0 + wi, j = j0 + wj;       // this wave's pair

    __shared__ float Apts[2][RS_N*2], Bpts[2][RS_N*2];
    __shared__ float4 Aseg[2][RS_N-1], Bseg[2][RS_N-1];
    __shared__ float  AInv[2][RS_N-1], BInv[2][RS_N-1];

    // early loads of precomputed partials (latency hidden under staging)
    float e_ip = 0.0f, e_rp = 0.0f, e_rg = 0.0f;
    if (l < 9) {
        e_ip = ws[INTP_OFF + l*7168 + i*64 + j];
        e_rp = ws[ROWP_OFF + i*9 + l];
        e_rg = ws[ROWG_OFF + j*9 + l];
    }

    // stage 4 polylines (192 float4)
    if (tid < 192) {
        int side = tid / 96;            // 0:A 1:B
        int r = (tid / 48) & 1;
        int o = tid % 48;
        const float4* src = (const float4*)(ws + (side ? GRS_OFF + (j0+r)*(RS_N*2)
                                                       : PRS_OFF + (i0+r)*(RS_N*2)));
        ((float4*)(side ? Bpts[r] : Apts[r]))[o] = src[o];
    }
    __syncthreads();
    // build 4 segment tables (380 entries)
    for (int q = tid; q < 4*(RS_N-1); q += 256) {
        int side = q / (2*(RS_N-1));
        int rr = (q / (RS_N-1)) & 1;
        int s = q % (RS_N-1);
        const float* P = side ? Bpts[rr] : Apts[rr];
        float ax = P[2*s], ay = P[2*s+1];
        float abx = P[2*s+2]-ax, aby = P[2*s+3]-ay;
        float inv = fast_rcp(fmaxf(abx*abx + aby*aby, 1e-8f));
        if (side) { Bseg[rr][s] = make_float4(ax,ay,abx,aby); BInv[rr][s] = inv; }
        else      { Aseg[rr][s] = make_float4(ax,ay,abx,aby); AInv[rr][s] = inv; }
    }
    __syncthreads();

    // chamfer: lanes 0-31 A-pts(wi) vs B-segs(wj); lanes 32-63 B-pts(wj) vs A-segs(wi)
    bool bSide = l >= 32;
    int h = l & 31;
    const float*  myP = bSide ? Bpts[wj] : Apts[wi];
    const float4* SG  = bSide ? Aseg[wi] : Bseg[wj];
    const float*  SI  = bSide ? AInv[wi] : BInv[wj];
    f32x2 px01 = { myP[6*h+0], myP[6*h+2] };
    f32x2 py01 = { myP[6*h+1], myP[6*h+3] };
    float px2 = myP[6*h+4], py2 = myP[6*h+5];
    f32x2 m01 = {3.0e38f, 3.0e38f};
    float m22 = 3.0e38f;
    #pragma unroll                       // FULL unroll: immediate LDS offsets, deep load-ahead
    for (int s = 0; s < RS_N-1; s++) {
        float4 sg = SG[s];
        float inv = SI[s];
        {
            f32x2 apx = px01 - sg.x;
            f32x2 apy = py01 - sg.y;
            f32x2 t = (apx*sg.z + apy*sg.w) * inv;
            t.x = fminf(fmaxf(t.x, 0.0f), 1.0f);
            t.y = fminf(fmaxf(t.y, 0.0f), 1.0f);
            f32x2 dx = apx - t*sg.z;
            f32x2 dy = apy - t*sg.w;
            f32x2 d2 = dx*dx + dy*dy;
            m01.x = fminf(m01.x, d2.x);
            m01.y = fminf(m01.y, d2.y);
        }
        {
            float apx = px2-sg.x, apy = py2-sg.y;
            float t = fminf(fmaxf((apx*sg.z + apy*sg.w)*inv, 0.0f), 1.0f);
            float dx = apx - t*sg.z, dy = apy - t*sg.w;
            m22 = fminf(m22, dx*dx + dy*dy);
        }
    }
    float cham = fast_sqrt(fmaxf(m01.x, 1e-12f)) + fast_sqrt(fmaxf(m01.y, 1e-12f))
               + fast_sqrt(fmaxf(m22, 1e-12f));

    // tangent + curvature: point-tasks p = l and l+64 (within this wave's pair)
    const float* AX = Apts[wi];
    const float* BX = Bpts[wj];
    float tsum = 0.0f, csum = 0.0f;
    #pragma unroll
    for (int rep = 0; rep < 2; rep++) {
        int p = l + rep*64;
        if (p < RS_N) {
            int pl = (p == 0) ? 0 : p-1;
            int pr = (p == RS_N-1) ? RS_N-1 : p+1;
            float tax = AX[2*pr]-AX[2*pl], tay = AX[2*pr+1]-AX[2*pl+1];
            float a2 = fmaxf(tax*tax + tay*tay, 1e-16f);
            float tbx = BX[2*pr]-BX[2*pl], tby = BX[2*pr+1]-BX[2*pl+1];
            float b2 = fmaxf(tbx*tbx + tby*tby, 1e-16f);
            // |dot| / (na*nb) with na,nb >= 1e-8 == |dot| * rsq(a2) * rsq(b2)
            tsum += fabsf(tax*tbx + tay*tby) * fast_rsq(a2) * fast_rsq(b2);
            if (p < RS_N-2) {
                float psx = AX[2*p+4] - 2.0f*AX[2*p+2] + AX[2*p];
                float psy = AX[2*p+5] - 2.0f*AX[2*p+3] + AX[2*p+1];
                float gsx = BX[2*p+4] - 2.0f*BX[2*p+2] + BX[2*p];
                float gsy = BX[2*p+5] - 2.0f*BX[2*p+3] + BX[2*p+1];
                csum += smooth_l1(psx - gsx) + smooth_l1(psy - gsy);
            }
        }
    }

    // per-wave reductions
    #pragma unroll
    for (int off = 32; off > 0; off >>= 1) {
        cham += __shfl_down(cham, off);
        tsum += __shfl_down(tsum, off);
        csum += __shfl_down(csum, off);
    }
    #pragma unroll
    for (int off = 8; off > 0; off >>= 1) {
        e_ip += __shfl_down(e_ip, off);
        e_rp += __shfl_down(e_rp, off);
        e_rg += __shfl_down(e_rg, off);
    }

    if (l == 0) {
        float sym  = cham * (1.0f/192.0f);
        float tanv = 1.0f - tsum * (1.0f/96.0f);
        float cuv  = csum * (1.0f/188.0f);
        float uni  = e_rp + e_rg - e_ip;
        float ovl  = 1.0f - e_ip / fmaxf(uni, 1e-8f);
        out[i * G_N + j] = PTS_W * sym + TAN_W * tanv + CURV_W * cuv + OVL_W * ovl;
    }
}

extern "C" void kernel_launch(void* const* d_in, const int* in_sizes, int n_in,
                              void* d_out, int out_size, void* d_ws, size_t ws_size,
                              hipStream_t stream) {
    (void)in_sizes; (void)n_in; (void)out_size; (void)ws_size;
    const float* pred = (const float*)d_in[0];
    const float* gt   = (const float*)d_in[1];
    const float* vis  = (const float*)d_in[2];
    float* out = (float*)d_out;
    float* ws  = (float*)d_ws;

    mask_kernel<<<(Q_N + G_N) * 9, 256, 0, stream>>>(pred, gt, vis, ws);
    inter_kernel<<<7 * 4 * 9, 64, 0, stream>>>(ws);
    pair_kernel<<<50 * 25, 256, 0, stream>>>(ws, out);
}

// Round 15
// 46.595 us; speedup vs baseline: 1.3410x; 1.3410x over previous
//
#include <hip/hip_runtime.h>
#include <hip/hip_bf16.h>
#include <math.h>

// Problem constants
#define Q_N 100
#define G_N 50
#define P_N 24
#define RS_N 96
#define GRID_N 9216
#define THICK 0.03f
#define SHARP 80.0f
#define PTS_W 5.0f
#define TAN_W 1.0f
#define CURV_W 0.5f
#define OVL_W 2.0f

// Workspace layout (float offsets). fp16 regions: n_ushorts/2 floats.
// PM padded to 112 rows, GM to 64 rows for 16x16 MFMA tiles (pad reads garbage,
// never flows into valid (i<100,j<50) outputs).
#define PRS_OFF  0                  // pred_rs: 100*192 = 19200 floats
#define GRS_OFF  19200              // gt_rs:   50*192  = 9600  -> 28800
#define PMB_OFF  28800              // PM fp16: 112*9216 ushort = 516096 f -> 544896
#define GMB_OFF  544896             // GM fp16:  64*9216 ushort = 294912 f -> 839808
#define ROWP_OFF 839808             // pred row-sum partials: 100*9 -> 840708
#define ROWG_OFF 840708             // gt   row-sum partials:  50*9 -> 841158
#define INTP_OFF 841216             // inter partials: 9 x 112 x 64 = 64512 -> 905728

typedef float    f32x2 __attribute__((ext_vector_type(2)));
typedef float    f32x4 __attribute__((ext_vector_type(4)));
typedef _Float16 f16x8 __attribute__((ext_vector_type(8)));

__device__ __forceinline__ float smooth_l1(float x) {
    float a = fabsf(x);
    return (a < 1.0f) ? 0.5f * a * a : a - 0.5f;
}
__device__ __forceinline__ float fast_rcp(float x) {
#if __has_builtin(__builtin_amdgcn_rcpf)
    return __builtin_amdgcn_rcpf(x);
#else
    return 1.0f / x;
#endif
}
__device__ __forceinline__ float fast_sqrt(float x) {
#if __has_builtin(__builtin_amdgcn_sqrtf)
    return __builtin_amdgcn_sqrtf(x);
#else
    return sqrtf(x);
#endif
}
__device__ __forceinline__ float fast_rsq(float x) {
#if __has_builtin(__builtin_amdgcn_rsqf)
    return __builtin_amdgcn_rsqf(x);
#else
    return 1.0f / sqrtf(x);
#endif
}

// ---- Kernel 1: soft masks (fp16) + row-sum partials + fused resample ----
__global__ __launch_bounds__(256)
void mask_kernel(const float* __restrict__ pred,
                 const float* __restrict__ gt,
                 const float* __restrict__ vis,
                 float* __restrict__ ws) {
    int row   = blockIdx.x / 9;         // 0..149
    int chunk = blockIdx.x % 9;         // 1024 grid pts each
    int tid = threadIdx.x;              // 0..255
    bool isPred = row < Q_N;
    __shared__ float ptx[P_N], pty[P_N], pvv[P_N];
    __shared__ float4 seg[P_N-1];
    __shared__ float  sinv[P_N-1];
    __shared__ int s_noseg;
    __shared__ float wsum[4];
    __shared__ float cum[P_N];
    __shared__ float s_total;

    if (tid < P_N) {
        const float* src = isPred ? pred + row * (P_N*2) : gt + (row - Q_N) * (P_N*2);
        float2 p = ((const float2*)src)[tid];
        ptx[tid] = p.x; pty[tid] = p.y;
    }
    if (tid == 0) {
        s_noseg = 1;
        if (isPred) {
            for (int k = 0; k < P_N; k++) pvv[k] = 1.0f;
        } else {
            const float* v = vis + (row - Q_N) * P_N;
            int cnt = 0;
            for (int k = 0; k < P_N; k++) {
                int r = (v[k] > 0.5f) ? 1 : 0;
                cnt += r;
                pvv[k] = (float)r;
            }
            if (cnt < 2) for (int k = 0; k < P_N; k++) pvv[k] = 1.0f;
        }
    }
    __syncthreads();
    if (tid < P_N-1) {
        bool v = pvv[tid] * pvv[tid+1] > 0.5f;
        if (v) {
            float ax = ptx[tid], ay = pty[tid];
            float abx = ptx[tid+1]-ax, aby = pty[tid+1]-ay;
            seg[tid] = make_float4(ax, ay, abx, aby);
            sinv[tid] = fast_rcp(fmaxf(abx*abx + aby*aby, 1e-8f));
            s_noseg = 0;                 // benign race: all writers write 0
        } else {
            seg[tid] = make_float4(1e18f, 1e18f, 0.0f, 0.0f);
            sinv[tid] = 0.0f;
        }
    }
    __syncthreads();

    int g0 = chunk * 1024 + tid * 4;    // 4 consecutive grid pts, same grid row
    float y  = (float)(g0 >> 7) * (1.0f/71.0f);
    float x0 = (float)(g0 & 127) * (1.0f/127.0f);
    f32x2 xs01 = { x0,                  x0 + 1.0f/127.0f };
    f32x2 xs23 = { x0 + 2.0f/127.0f,    x0 + 3.0f/127.0f };
    f32x2 m01 = {3.0e38f, 3.0e38f}, m23 = {3.0e38f, 3.0e38f};
    #pragma unroll
    for (int k = 0; k < P_N-1; k++) {
        float4 sg = seg[k];
        float inv = sinv[k];
        float apy = y - sg.y;
        float dwy = apy * sg.w;
        f32x2 apx01 = xs01 - sg.x;
        f32x2 apx23 = xs23 - sg.x;
        f32x2 t01 = (apx01*sg.z + dwy) * inv;
        f32x2 t23 = (apx23*sg.z + dwy) * inv;
        t01.x = fminf(fmaxf(t01.x, 0.0f), 1.0f);
        t01.y = fminf(fmaxf(t01.y, 0.0f), 1.0f);
        t23.x = fminf(fmaxf(t23.x, 0.0f), 1.0f);
        t23.y = fminf(fmaxf(t23.y, 0.0f), 1.0f);
        f32x2 dx01 = apx01 - t01*sg.z;
        f32x2 dy01 = apy   - t01*sg.w;
        f32x2 dx23 = apx23 - t23*sg.z;
        f32x2 dy23 = apy   - t23*sg.w;
        f32x2 d01 = dx01*dx01 + dy01*dy01;
        f32x2 d23 = dx23*dx23 + dy23*dy23;
        m01.x = fminf(m01.x, d01.x); m01.y = fminf(m01.y, d01.y);
        m23.x = fminf(m23.x, d23.x); m23.y = fminf(m23.y, d23.y);
    }
    float m2[4] = { m01.x, m01.y, m23.x, m23.y };
    if (s_noseg) {
        float xs[4] = { xs01.x, xs01.y, xs23.x, xs23.y };
        #pragma unroll
        for (int u = 0; u < 4; u++) m2[u] = 3.0e38f;
        for (int k = 0; k < P_N; k++) {
            if (pvv[k] > 0.5f) {
                #pragma unroll
                for (int u = 0; u < 4; u++) {
                    float dx = xs[u] - ptx[k], dy = y - pty[k];
                    m2[u] = fminf(m2[u], dx*dx + dy*dy);
                }
            }
        }
    }
    ushort4 o;
    unsigned short* ov = &o.x;
    float lsum = 0.0f;
    #pragma unroll
    for (int u = 0; u < 4; u++) {
        float mind = fast_sqrt(fmaxf(m2[u], 1e-12f));
        float z = (THICK - mind) * SHARP;
        float s = fast_rcp(1.0f + __expf(-z));
        _Float16 h = (_Float16)s;                  // RNE f32->f16
        ov[u] = __builtin_bit_cast(unsigned short, h);
        lsum += (float)h;                          // sums consistent with quantized masks
    }
    unsigned short* base = (unsigned short*)(ws + (isPred ? PMB_OFF : GMB_OFF))
                         + (size_t)(isPred ? row : row - Q_N) * GRID_N;
    ((ushort4*)base)[g0 >> 2] = o;

    // deterministic block reduction of lsum
    #pragma unroll
    for (int off = 32; off > 0; off >>= 1) lsum += __shfl_down(lsum, off);
    if ((tid & 63) == 0) wsum[tid >> 6] = lsum;
    __syncthreads();
    if (tid == 0) {
        float s = (wsum[0] + wsum[1]) + (wsum[2] + wsum[3]);
        if (isPred) ws[ROWP_OFF + row*9 + chunk] = s;
        else        ws[ROWG_OFF + (row - Q_N)*9 + chunk] = s;
    }

    // ---- fused resample: only chunk-0 blocks ----
    if (chunk == 0) {
        if (tid == 0) {
            float c = 0.0f;
            cum[0] = 0.0f;
            for (int k = 0; k < P_N-1; k++) {
                float dx = ptx[k+1]-ptx[k], dy = pty[k+1]-pty[k];
                float len = sqrtf(fmaxf(dx*dx + dy*dy, 1e-12f));  // _safe_norm (keep IEEE)
                float valid = pvv[k]*pvv[k+1];
                c += len * valid;
                cum[k+1] = c;
            }
            s_total = c;
        }
        __syncthreads();
        float total = s_total;
        if (tid < RS_N) {
            float ox, oy;
            if (total < 1e-8f) {
                ox = ptx[0]; oy = pty[0];
            } else {
                float t = ((float)tid / 95.0f) * total;
                // searchsorted(cum, t, side='right') - 1 == count(cum <= t) - 1
                int idx = -1;
                for (int k = 0; k < P_N; k++) idx += (cum[k] <= t) ? 1 : 0;
                idx = min(max(idx, 0), P_N-2);
                float lt = cum[idx], rt = cum[idx+1];
                float alpha = (t - lt) / fmaxf(rt - lt, 1e-8f);
                ox = ptx[idx] + alpha * (ptx[idx+1]-ptx[idx]);
                oy = pty[idx] + alpha * (pty[idx+1]-pty[idx]);
            }
            float* dst = isPred ? ws + PRS_OFF + row * (RS_N*2)
                                : ws + GRS_OFF + (row - Q_N) * (RS_N*2);
            dst[2*tid]   = ox;
            dst[2*tid+1] = oy;
        }
    }
}

// ---- Kernel 2: inter = PM (fp16) x GM^T (fp16) via MFMA, K-split x9 ----
__global__ __launch_bounds__(64)
void inter_kernel(float* __restrict__ ws) {
    int bid = blockIdx.x;               // 7 x 4 x 9 = 252
    int mt = bid % 7;
    int nt = (bid / 7) & 3;
    int kc = bid / 28;                  // 0..8
    int l = threadIdx.x;
    const unsigned short* PMB = (const unsigned short*)(ws + PMB_OFF);
    const unsigned short* GMB = (const unsigned short*)(ws + GMB_OFF);
    int i0 = mt*16, j0 = nt*16, k0 = kc*1024;
    const f16x8* pa = (const f16x8*)(PMB + (size_t)(i0 + (l & 15)) * GRID_N + k0 + 8*(l >> 4));
    const f16x8* pb = (const f16x8*)(GMB + (size_t)(j0 + (l & 15)) * GRID_N + k0 + 8*(l >> 4));
    f32x4 acc = {0.0f, 0.0f, 0.0f, 0.0f};
    #pragma unroll 8
    for (int s = 0; s < 32; s++) {
        acc = __builtin_amdgcn_mfma_f32_16x16x32_f16(pa[s*4], pb[s*4], acc, 0, 0, 0);
    }
    // D: col = l&15, row = 4*(l>>4) + v
    float* dst = ws + INTP_OFF + kc * 7168;     // 112*64
    int r0 = 4*(l >> 4), c = l & 15;
    #pragma unroll
    for (int v = 0; v < 4; v++) {
        dst[(i0 + r0 + v) * 64 + (j0 + c)] = acc[v];
    }
}

// ---- Kernel 3: 2x2 pair tile per 256-thread block; unroll-5 chamfer ----
__global__ __launch_bounds__(256, 2)       // cap VGPR at 128: no occupancy cliff
void pair_kernel(const float* __restrict__ ws, float* __restrict__ out) {
    int bi = blockIdx.x / 25;           // i0 = 2*bi
    int bj = blockIdx.x % 25;           // j0 = 2*bj
    int i0 = bi*2, j0 = bj*2;
    int tid = threadIdx.x;
    int w = tid >> 6;                   // wave 0..3
    int l = tid & 63;
    int wi = w >> 1, wj = w & 1;
    int i = i0 + wi, j = j0 + wj;       // this wave's pair

    __shared__ float Apts[2][RS_N*2], Bpts[2][RS_N*2];
    __shared__ float4 Aseg[2][RS_N-1], Bseg[2][RS_N-1];
    __shared__ float  AInv[2][RS_N-1], BInv[2][RS_N-1];

    // early loads of precomputed partials (latency hidden under staging)
    float e_ip = 0.0f, e_rp = 0.0f, e_rg = 0.0f;
    if (l < 9) {
        e_ip = ws[INTP_OFF + l*7168 + i*64 + j];
        e_rp = ws[ROWP_OFF + i*9 + l];
        e_rg = ws[ROWG_OFF + j*9 + l];
    }

    // stage 4 polylines (192 float4) AND build 4 seg tables from global (L2-hot)
    // concurrently -> single barrier
    if (tid < 192) {
        int side = tid / 96;            // 0:A 1:B
        int r = (tid / 48) & 1;
        int o = tid % 48;
        const float4* src = (const float4*)(ws + (side ? GRS_OFF + (j0+r)*(RS_N*2)
                                                       : PRS_OFF + (i0+r)*(RS_N*2)));
        ((float4*)(side ? Bpts[r] : Apts[r]))[o] = src[o];
    }
    for (int q = tid; q < 4*(RS_N-1); q += 256) {
        int side = q / (2*(RS_N-1));
        int rr = (q / (RS_N-1)) & 1;
        int s = q % (RS_N-1);
        const float* G = ws + (side ? GRS_OFF + (size_t)(j0+rr)*(RS_N*2)
                                    : PRS_OFF + (size_t)(i0+rr)*(RS_N*2));
        float2 p0 = ((const float2*)G)[s];
        float2 p1 = ((const float2*)G)[s+1];
        float abx = p1.x - p0.x, aby = p1.y - p0.y;
        float inv = fast_rcp(fmaxf(abx*abx + aby*aby, 1e-8f));
        if (side) { Bseg[rr][s] = make_float4(p0.x,p0.y,abx,aby); BInv[rr][s] = inv; }
        else      { Aseg[rr][s] = make_float4(p0.x,p0.y,abx,aby); AInv[rr][s] = inv; }
    }
    __syncthreads();

    // chamfer: lanes 0-31 A-pts(wi) vs B-segs(wj); lanes 32-63 B-pts(wj) vs A-segs(wi)
    bool bSide = l >= 32;
    int h = l & 31;
    const float*  myP = bSide ? Bpts[wj] : Apts[wi];
    const float4* SG  = bSide ? Aseg[wi] : Bseg[wj];
    const float*  SI  = bSide ? AInv[wi] : BInv[wj];
    f32x2 px01 = { myP[6*h+0], myP[6*h+2] };
    f32x2 py01 = { myP[6*h+1], myP[6*h+3] };
    float px2 = myP[6*h+4], py2 = myP[6*h+5];
    f32x2 m01 = {3.0e38f, 3.0e38f};
    float m22 = 3.0e38f;
    #pragma unroll 5
    for (int s = 0; s < RS_N-1; s++) {
        float4 sg = SG[s];
        float inv = SI[s];
        {
            f32x2 apx = px01 - sg.x;
            f32x2 apy = py01 - sg.y;
            f32x2 t = (apx*sg.z + apy*sg.w) * inv;
            t.x = fminf(fmaxf(t.x, 0.0f), 1.0f);
            t.y = fminf(fmaxf(t.y, 0.0f), 1.0f);
            f32x2 dx = apx - t*sg.z;
            f32x2 dy = apy - t*sg.w;
            f32x2 d2 = dx*dx + dy*dy;
            m01.x = fminf(m01.x, d2.x);
            m01.y = fminf(m01.y, d2.y);
        }
        {
            float apx = px2-sg.x, apy = py2-sg.y;
            float t = fminf(fmaxf((apx*sg.z + apy*sg.w)*inv, 0.0f), 1.0f);
            float dx = apx - t*sg.z, dy = apy - t*sg.w;
            m22 = fminf(m22, dx*dx + dy*dy);
        }
    }
    float cham = fast_sqrt(fmaxf(m01.x, 1e-12f)) + fast_sqrt(fmaxf(m01.y, 1e-12f))
               + fast_sqrt(fmaxf(m22, 1e-12f));

    // tangent + curvature: point-tasks p = l and l+64 (within this wave's pair)
    const float* AX = Apts[wi];
    const float* BX = Bpts[wj];
    float tsum = 0.0f, csum = 0.0f;
    #pragma unroll
    for (int rep = 0; rep < 2; rep++) {
        int p = l + rep*64;
        if (p < RS_N) {
            int pl = (p == 0) ? 0 : p-1;
            int pr = (p == RS_N-1) ? RS_N-1 : p+1;
            float tax = AX[2*pr]-AX[2*pl], tay = AX[2*pr+1]-AX[2*pl+1];
            float a2 = fmaxf(tax*tax + tay*tay, 1e-16f);
            float tbx = BX[2*pr]-BX[2*pl], tby = BX[2*pr+1]-BX[2*pl+1];
            float b2 = fmaxf(tbx*tbx + tby*tby, 1e-16f);
            // |dot|/(na*nb), na,nb clamped at 1e-8 == |dot|*rsq(a2)*rsq(b2) with a2,b2 >= 1e-16
            tsum += fabsf(tax*tbx + tay*tby) * fast_rsq(a2) * fast_rsq(b2);
            if (p < RS_N-2) {
                float psx = AX[2*p+4] - 2.0f*AX[2*p+2] + AX[2*p];
                float psy = AX[2*p+5] - 2.0f*AX[2*p+3] + AX[2*p+1];
                float gsx = BX[2*p+4] - 2.0f*BX[2*p+2] + BX[2*p];
                float gsy = BX[2*p+5] - 2.0f*BX[2*p+3] + BX[2*p+1];
                csum += smooth_l1(psx - gsx) + smooth_l1(psy - gsy);
            }
        }
    }

    // per-wave reductions
    #pragma unroll
    for (int off = 32; off > 0; off >>= 1) {
        cham += __shfl_down(cham, off);
        tsum += __shfl_down(tsum, off);
        csum += __shfl_down(csum, off);
    }
    #pragma unroll
    for (int off = 8; off > 0; off >>= 1) {
        e_ip += __shfl_down(e_ip, off);
        e_rp += __shfl_down(e_rp, off);
        e_rg += __shfl_down(e_rg, off);
    }

    if (l == 0) {
        float sym  = cham * (1.0f/192.0f);
        float tanv = 1.0f - tsum * (1.0f/96.0f);
        float cuv  = csum * (1.0f/188.0f);
        float uni  = e_rp + e_rg - e_ip;
        float ovl  = 1.0f - e_ip / fmaxf(uni, 1e-8f);
        out[i * G_N + j] = PTS_W * sym + TAN_W * tanv + CURV_W * cuv + OVL_W * ovl;
    }
}

extern "C" void kernel_launch(void* const* d_in, const int* in_sizes, int n_in,
                              void* d_out, int out_size, void* d_ws, size_t ws_size,
                              hipStream_t stream) {
    (void)in_sizes; (void)n_in; (void)out_size; (void)ws_size;
    const float* pred = (const float*)d_in[0];
    const float* gt   = (const float*)d_in[1];
    const float* vis  = (const float*)d_in[2];
    float* out = (float*)d_out;
    float* ws  = (float*)d_ws;

    mask_kernel<<<(Q_N + G_N) * 9, 256, 0, stream>>>(pred, gt, vis, ws);
    inter_kernel<<<7 * 4 * 9, 64, 0, stream>>>(ws);
    pair_kernel<<<50 * 25, 256, 0, stream>>>(ws, out);
}